// Round 12
// baseline (930.086 us; speedup 1.0000x reference)
//
#include <hip/hip_runtime.h>
#include <hip/hip_bf16.h>
#include <math.h>

// Problem constants
#define N_TOK 32768
#define DIMD  512
#define FFD   2048
#define NE    8
#define CAPQ  5120
#define TPE2  20          // CAPQ / 256 row-tiles per expert
#define NBLK  128         // scan blocks (256 tokens each)

typedef __attribute__((ext_vector_type(8))) short          bf16x8;
typedef __attribute__((ext_vector_type(4))) float          f32x4;
typedef __attribute__((ext_vector_type(8))) unsigned short u16x8;

__device__ __forceinline__ unsigned short f2bf(float f) {
  union { float f; unsigned u; } v; v.f = f;
  unsigned r = v.u + 0x7fffu + ((v.u >> 16) & 1u);   // RNE (finite values only)
  return (unsigned short)(r >> 16);
}

// tanh-gelu in sigmoid form: 0.5v(1+tanh u) == v * sigma(2u), exact identity.
__device__ __forceinline__ float gelu_f(float v) {
  float t = v * v;
  float q = fmaf(-0.0713548162f, t, -1.5957691216f);   // -2*(a + b*t)
  float w = v * q;                                      // -2u
  float d = 1.0f + __expf(w);
  return v * __builtin_amdgcn_rcpf(d);
}

// async global->LDS, 16B/lane; LDS dest is wave-uniform base + lane*16
#define GLL16(gsrc, ldst)                                                      \
  __builtin_amdgcn_global_load_lds(                                            \
      (const __attribute__((address_space(1))) void*)(gsrc),                   \
      (__attribute__((address_space(3))) void*)(ldst), 16, 0, 0)

// ---- merged tiled transpose + f32->bf16: 17 slabs (1 shared + 8 + 8) -----
__global__ __launch_bounds__(256) void transpose_cvt3_kernel(
    const float* __restrict__ s0, const float* __restrict__ s1,
    const float* __restrict__ s2,
    unsigned short* __restrict__ d0, unsigned short* __restrict__ d1,
    unsigned short* __restrict__ d2, int R, int C) {
  __shared__ unsigned short tile[32][33];
  const int z = blockIdx.z;
  const float* in; unsigned short* out;
  if (z == 0)      { in = s0;                            out = d0; }
  else if (z <= 8) { in = s1 + (size_t)(z - 1) * R * C;  out = d1 + (size_t)(z - 1) * R * C; }
  else             { in = s2 + (size_t)(z - 9) * R * C;  out = d2 + (size_t)(z - 9) * R * C; }
  int c0 = blockIdx.x * 32, r0 = blockIdx.y * 32;
  int tx = threadIdx.x & 31, ty = threadIdx.x >> 5;   // 32x8
  #pragma unroll
  for (int i = 0; i < 4; i++) {
    int r = ty + i * 8;
    tile[r][tx] = f2bf(in[(size_t)(r0 + r) * C + c0 + tx]);
  }
  __syncthreads();
  #pragma unroll
  for (int i = 0; i < 4; i++) {
    int c = ty + i * 8;
    out[(size_t)(c0 + c) * R + r0 + tx] = tile[tx][c];
  }
}

// ---- router: logits, softmax, top-1, gate (both banks) + x->bf16 fused ---
__global__ __launch_bounds__(256) void router_kernel(
    const float* __restrict__ x, unsigned short* __restrict__ xb,
    const float* __restrict__ WrS, const float* __restrict__ brS,
    const float* __restrict__ WrF, const float* __restrict__ brF,
    int* __restrict__ expS, float* __restrict__ gateS,
    int* __restrict__ expF, float* __restrict__ gateF) {
  __shared__ float wS[DIMD * NE], wF[DIMD * NE];
  for (int i = threadIdx.x; i < DIMD * NE / 4; i += 256) {
    ((float4*)wS)[i] = ((const float4*)WrS)[i];
    ((float4*)wF)[i] = ((const float4*)WrF)[i];
  }
  __syncthreads();
  const int w = threadIdx.x >> 6, lane = threadIdx.x & 63;
  const int n0 = (blockIdx.x * 4 + w) * 8;       // 8 tokens per wave
  for (int t = 0; t < 8; t++) {
    const int n = n0 + t;
    const float* xr = x + (size_t)n * DIMD + lane * 8;
    float4 xa = *(const float4*)xr, xb4 = *(const float4*)(xr + 4);
    float xv[8] = {xa.x, xa.y, xa.z, xa.w, xb4.x, xb4.y, xb4.z, xb4.w};
    u16x8 xo;
    #pragma unroll
    for (int j = 0; j < 8; j++) xo[j] = f2bf(xv[j]);
    *(u16x8*)(xb + (size_t)n * DIMD + lane * 8) = xo;   // fused x->bf16
    float aS[NE], aF[NE];
    #pragma unroll
    for (int e = 0; e < NE; e++) { aS[e] = 0.f; aF[e] = 0.f; }
    #pragma unroll
    for (int j = 0; j < 8; j++) {
      const int k = lane * 8 + j;
      const float* ps = &wS[k * NE];
      const float* pf = &wF[k * NE];
      #pragma unroll
      for (int e = 0; e < NE; e++) { aS[e] += xv[j] * ps[e]; aF[e] += xv[j] * pf[e]; }
    }
    #pragma unroll
    for (int e = 0; e < NE; e++)
      for (int off = 32; off; off >>= 1) {
        aS[e] += __shfl_xor(aS[e], off);
        aF[e] += __shfl_xor(aF[e], off);
      }
    if (lane == 0) {
      float l[NE];
      #pragma unroll
      for (int e = 0; e < NE; e++) l[e] = aS[e] + brS[e];
      float m = l[0]; int am = 0;
      #pragma unroll
      for (int e = 1; e < NE; e++) if (l[e] > m) { m = l[e]; am = e; }  // first max
      float s = 0.f;
      #pragma unroll
      for (int e = 0; e < NE; e++) s += __expf(l[e] - m);
      expS[n] = am; gateS[n] = __builtin_amdgcn_rcpf(s);
      #pragma unroll
      for (int e = 0; e < NE; e++) l[e] = aF[e] + brF[e];
      m = l[0]; am = 0;
      #pragma unroll
      for (int e = 1; e < NE; e++) if (l[e] > m) { m = l[e]; am = e; }
      s = 0.f;
      #pragma unroll
      for (int e = 0; e < NE; e++) s += __expf(l[e] - m);
      expF[n] = am; gateF[n] = __builtin_amdgcn_rcpf(s);
    }
  }
}

// ------------- parallel stable capacity scan (3 kernels) ------------------
__global__ __launch_bounds__(256) void scan_count_kernel(
    const int* __restrict__ expS, const int* __restrict__ expF,
    int* __restrict__ blockcnt) {
  const int b = blockIdx.x, t = threadIdx.x;
  const int w = t >> 6, lane = t & 63;
  const int eS_ = expS[b * 256 + t], eF_ = expF[b * 256 + t];
  __shared__ int cnt[2][4][NE];
  #pragma unroll
  for (int q = 0; q < NE; q++) {
    unsigned long long mS = __ballot(eS_ == q);
    unsigned long long mF = __ballot(eF_ == q);
    if (lane == 0) { cnt[0][w][q] = __popcll(mS); cnt[1][w][q] = __popcll(mF); }
  }
  __syncthreads();
  if (t < 16) {
    const int bank = t >> 3, q = t & 7;
    blockcnt[bank * NBLK * NE + b * NE + q] =
        cnt[bank][0][q] + cnt[bank][1][q] + cnt[bank][2][q] + cnt[bank][3][q];
  }
}

// meta layout: [cntS 8][hbS 8][cntF 8][hbF 8]; hidden bases 256-aligned
__global__ __launch_bounds__(64) void scan_base_kernel(
    const int* __restrict__ blockcnt, int* __restrict__ blockbase,
    int* __restrict__ meta) {
  __shared__ int tot[2][NE];
  const int t = threadIdx.x;
  if (t < 16) {
    const int bank = t >> 3, q = t & 7;
    int run = 0;
    for (int i = 0; i < NBLK; i++) {
      int v = blockcnt[bank * NBLK * NE + i * NE + q];
      blockbase[bank * NBLK * NE + i * NE + q] = run;
      run += v;
    }
    tot[bank][q] = run;
  }
  __syncthreads();
  if (t == 0) {
    int hb_ = 0;
    for (int q = 0; q < NE; q++) {
      int cc = tot[0][q]; if (cc > CAPQ) cc = CAPQ;
      meta[q] = cc; meta[NE + q] = hb_;
      hb_ += ((cc + 255) >> 8) << 8;          // 256-aligned hidden base
    }
    hb_ = 0;
    for (int q = 0; q < NE; q++) {
      int cc = tot[1][q]; if (cc > CAPQ) cc = CAPQ;
      meta[2 * NE + q] = cc; meta[3 * NE + q] = hb_;
      hb_ += ((cc + 255) >> 8) << 8;
    }
  }
}

__global__ __launch_bounds__(256) void scan_write_kernel(
    const int* __restrict__ expS, const int* __restrict__ expF,
    const int* __restrict__ blockbase,
    int* __restrict__ idxS, int* __restrict__ idxF) {
  const int b = blockIdx.x, t = threadIdx.x;
  const int w = t >> 6, lane = t & 63;
  const int n = b * 256 + t;
  const int eS_ = expS[n], eF_ = expF[n];
  __shared__ int wcnt[2][4][NE];
  const unsigned long long ltmask = ((unsigned long long)1 << lane) - 1;
  int rS = 0, rF = 0;
  #pragma unroll
  for (int q = 0; q < NE; q++) {
    unsigned long long mS = __ballot(eS_ == q);
    unsigned long long mF = __ballot(eF_ == q);
    if (eS_ == q) rS = __popcll(mS & ltmask);
    if (eF_ == q) rF = __popcll(mF & ltmask);
    if (lane == 0) { wcnt[0][w][q] = __popcll(mS); wcnt[1][w][q] = __popcll(mF); }
  }
  __syncthreads();
  int pS = blockbase[0 * NBLK * NE + b * NE + eS_] + rS;
  int pF = blockbase[1 * NBLK * NE + b * NE + eF_] + rF;
  #pragma unroll
  for (int wv = 0; wv < 4; wv++) {
    if (wv < w) { pS += wcnt[0][wv][eS_]; pF += wcnt[1][wv][eF_]; }
  }
  if (pS < CAPQ) idxS[eS_ * CAPQ + pS] = n;
  if (pF < CAPQ) idxF[eF_ * CAPQ + pF] = n;
}

// --- MFMA GEMM, 256x256 tile, BK=32, 16 waves (4x4 of 64x64), dbuf -------
// 131 FLOP per staged byte (2x the 128x128/BK64 config) at UNCHANGED
// 2 blocks/CU (LDS 64 KB). Staging: 1 A + 1 B GLL16 per thread per tile;
// counted vmcnt(2) pipeline. BK=32 involution swizzle (R10-proven):
// stored k-chunk = c ^ ((row>>1)&3); source pre-swizzle (tid&3)^((tid>>3)&3);
// read kch = grp ^ ((l15>>1)&3).
// EPI 0: C = gelu(A@Bt^T + bias) -> hidden bf16     (K=DIMD, NC=FFD)
// EPI 1: out = A@Bt^T + bias (f32 write)            (K=FFD,  NC=DIMD)
// EPI 2: out[tok] += (A@Bt^T + bias) * gate[tok]    (K=FFD,  NC=DIMD)
template <int EPI, bool GATHER, bool BANKED>
__global__ __launch_bounds__(1024, 4) void gemm_kernel(
    const unsigned short* __restrict__ A,
    const unsigned short* __restrict__ Bt,   // [(e)][NC][K] bf16 (pre-transposed)
    const float* __restrict__ bias,          // [(e)][NC]
    const int* __restrict__ idx, const int* __restrict__ cnt,
    const int* __restrict__ hb, const float* __restrict__ gate,
    unsigned short* __restrict__ hidOut, float* __restrict__ fOut) {
  constexpr int K  = (EPI == 0) ? DIMD : FFD;
  constexpr int NC = (EPI == 0) ? FFD : DIMD;
  constexpr int NT = K / 32;                  // 16 (FFN1) or 64 (FFN2)

  __shared__ __align__(16) unsigned short lA[2][256 * 32];  // 2 x 16 KiB
  __shared__ __align__(16) unsigned short lB[2][256 * 32];  // 2 x 16 KiB

  const int tid = threadIdx.x;
  const int w = tid >> 6, lane = tid & 63;

  // bijective XCD-chunked block swizzle (m204)
  const int gx = gridDim.x;
  const int nwg = gx * gridDim.y;
  int flat = blockIdx.y * gx + blockIdx.x;
  {
    const int q8 = nwg >> 3, r8 = nwg & 7;
    const int xcd = flat & 7, loc = flat >> 3;
    flat = (xcd < r8 ? xcd * (q8 + 1) : r8 * (q8 + 1) + (xcd - r8) * q8) + loc;
  }
  const int bx = flat % gx, by = flat / gx;

  int e = 0, r0, cnte = 0;
  if (BANKED) {
    e = by / TPE2;
    r0 = (by - e * TPE2) * 256;
    cnte = cnt[e];
    if (r0 >= cnte) return;
  } else {
    r0 = by * 256;
  }

  // --- staging: thread covers row tid>>2 of A and B tiles; chunk pre-swz
  const int srow = tid >> 2;                       // 0..255
  const int gch  = (tid & 3) ^ ((tid >> 3) & 3);   // inverse of read swizzle
  const unsigned short* aSrc;
  const unsigned short* bSrc;
  const size_t bcol0 = (size_t)(BANKED ? e * NC : 0) + (size_t)bx * 256;
  {
    size_t arow;
    if (GATHER) {
      int s = r0 + srow;
      int tok = (s < cnte) ? idx[e * CAPQ + s] : 0;
      arow = (size_t)tok;
    } else if (BANKED) {
      arow = (size_t)(hb[e] + r0 + srow);
    } else {
      arow = (size_t)(r0 + srow);
    }
    aSrc = A + arow * K + gch * 8;
    bSrc = Bt + (bcol0 + srow) * K + gch * 8;
  }

  f32x4 acc[4][4];
  #pragma unroll
  for (int m = 0; m < 4; m++)
    #pragma unroll
    for (int n = 0; n < 4; n++) acc[m][n] = (f32x4){0.f, 0.f, 0.f, 0.f};

  const int wr = w >> 2, wc = w & 3;       // wave: rows wr*64.., cols wc*64..
  const int grp = lane >> 4, l15 = lane & 15;
  const int kch = grp ^ ((l15 >> 1) & 3);  // swizzled k-chunk (R10-proven)
  int aoff[4], boff[4];
  #pragma unroll
  for (int m = 0; m < 4; m++) aoff[m] = (wr * 64 + m * 16 + l15) * 32 + kch * 8;
  #pragma unroll
  for (int n = 0; n < 4; n++) boff[n] = (wc * 64 + n * 16 + l15) * 32 + kch * 8;

  auto stage = [&](int buf, int k0) {
    char* la = (char*)&lA[buf][0] + (unsigned)w * 1024;
    char* lb = (char*)&lB[buf][0] + (unsigned)w * 1024;
    GLL16(aSrc + k0, la);
    GLL16(bSrc + k0, lb);
  };

  stage(0, 0);                                 // 2 loads in flight
  int cur = 0;
  #pragma unroll 1
  for (int t = 0; t < NT; t++) {
    if (t + 1 < NT) {
      stage(cur ^ 1, (t + 1) * 32);            // +2 loads (4 in flight)
      asm volatile("s_waitcnt vmcnt(2)" ::: "memory");   // tile t landed
    } else {
      asm volatile("s_waitcnt vmcnt(0)" ::: "memory");   // last tile drains
    }
    __builtin_amdgcn_s_barrier();              // publish tile t across waves
    __builtin_amdgcn_sched_barrier(0);
    const unsigned short* A_ = &lA[cur][0];
    const unsigned short* B_ = &lB[cur][0];
    bf16x8 af[4], bfv[4];
    #pragma unroll
    for (int m = 0; m < 4; m++) af[m] = *(const bf16x8*)&A_[aoff[m]];
    #pragma unroll
    for (int n = 0; n < 4; n++) bfv[n] = *(const bf16x8*)&B_[boff[n]];
    __builtin_amdgcn_s_setprio(1);
    #pragma unroll
    for (int m = 0; m < 4; m++)
      #pragma unroll
      for (int n = 0; n < 4; n++)
        acc[m][n] = __builtin_amdgcn_mfma_f32_16x16x32_bf16(af[m], bfv[n], acc[m][n], 0, 0, 0);
    __builtin_amdgcn_s_setprio(0);
    __builtin_amdgcn_sched_barrier(0);
    __builtin_amdgcn_s_barrier();              // all waves done reading buf[cur]
    cur ^= 1;
  }

  // --- epilogue: C/D layout col=lane&15, row=(lane>>4)*4+j (m89-verified)
  const int grp4 = grp * 4;
  if constexpr (EPI == 0) {
    const size_t hrow0 = (size_t)((BANKED ? hb[e] : 0) + r0);
    const float* bP2 = bias + (BANKED ? e * NC : 0) + bx * 256;
    #pragma unroll
    for (int m = 0; m < 4; m++)
      #pragma unroll
      for (int j = 0; j < 4; j++) {
        const int rloc = wr * 64 + m * 16 + grp4 + j;
        unsigned short* hrow = hidOut + (hrow0 + rloc) * FFD + bx * 256;
        #pragma unroll
        for (int n = 0; n < 4; n++) {
          const int cloc = wc * 64 + n * 16 + l15;
          float v = acc[m][n][j] + bP2[cloc];
          hrow[cloc] = f2bf(gelu_f(v));
        }
      }
  } else if constexpr (EPI == 1) {
    const float* bP2 = bias + bx * 256;
    #pragma unroll
    for (int m = 0; m < 4; m++)
      #pragma unroll
      for (int j = 0; j < 4; j++) {
        const int rloc = wr * 64 + m * 16 + grp4 + j;
        float* orow = fOut + (size_t)(r0 + rloc) * DIMD + bx * 256;
        #pragma unroll
        for (int n = 0; n < 4; n++) {
          const int cloc = wc * 64 + n * 16 + l15;
          orow[cloc] = acc[m][n][j] + bP2[cloc];
        }
      }
  } else {
    const float* bP2 = bias + e * NC + bx * 256;
    const int* idxe = idx + e * CAPQ + r0;
    #pragma unroll
    for (int m = 0; m < 4; m++)
      #pragma unroll
      for (int j = 0; j < 4; j++) {
        const int rloc = wr * 64 + m * 16 + grp4 + j;
        if (r0 + rloc < cnte) {
          const int tok = idxe[rloc];
          const float gv = gate[tok];
          float* orow = fOut + (size_t)tok * DIMD + bx * 256;
          #pragma unroll
          for (int n = 0; n < 4; n++) {
            const int cloc = wc * 64 + n * 16 + l15;
            orow[cloc] += (acc[m][n][j] + bP2[cloc]) * gv;  // unique (tok,col)
          }
        }
      }
  }
}

extern "C" void kernel_launch(void* const* d_in, const int* in_sizes, int n_in,
                              void* d_out, int out_size, void* d_ws, size_t ws_size,
                              hipStream_t stream) {
  const float* x   = (const float*)d_in[0];
  const float* WrS = (const float*)d_in[1];
  const float* brS = (const float*)d_in[2];
  const float* WrF = (const float*)d_in[3];
  const float* brF = (const float*)d_in[4];
  const float* Ws1 = (const float*)d_in[5];
  const float* bs1 = (const float*)d_in[6];
  const float* Ws2 = (const float*)d_in[7];
  const float* bs2 = (const float*)d_in[8];
  const float* W1s = (const float*)d_in[9];
  const float* b1s = (const float*)d_in[10];
  const float* W2s = (const float*)d_in[11];
  const float* b2s = (const float*)d_in[12];
  const float* W1f = (const float*)d_in[13];
  const float* b1f = (const float*)d_in[14];
  const float* W2f = (const float*)d_in[15];
  const float* b2f = (const float*)d_in[16];
  float* out = (float*)d_out;

  char* ws = (char*)d_ws;
  size_t off = 0;
  auto alloc = [&](size_t b) { char* p = ws + off; off += (b + 255) & ~(size_t)255; return p; };
  unsigned short* xb     = (unsigned short*)alloc((size_t)N_TOK * DIMD * 2);
  unsigned short* ws1t   = (unsigned short*)alloc((size_t)FFD * DIMD * 2);
  unsigned short* ws2t   = (unsigned short*)alloc((size_t)DIMD * FFD * 2);
  unsigned short* w1st   = (unsigned short*)alloc((size_t)NE * FFD * DIMD * 2);
  unsigned short* w2st   = (unsigned short*)alloc((size_t)NE * DIMD * FFD * 2);
  unsigned short* w1ft   = (unsigned short*)alloc((size_t)NE * FFD * DIMD * 2);
  unsigned short* w2ft   = (unsigned short*)alloc((size_t)NE * DIMD * FFD * 2);
  unsigned short* hidden = (unsigned short*)alloc((size_t)(N_TOK + NE * 256) * FFD * 2);
  int*   expS = (int*)alloc((size_t)N_TOK * 4);
  int*   expF = (int*)alloc((size_t)N_TOK * 4);
  float* gS   = (float*)alloc((size_t)N_TOK * 4);
  float* gF   = (float*)alloc((size_t)N_TOK * 4);
  int*   idxS = (int*)alloc((size_t)NE * CAPQ * 4);
  int*   idxF = (int*)alloc((size_t)NE * CAPQ * 4);
  int*   meta = (int*)alloc(4 * NE * 4);
  int*   blockcnt  = (int*)alloc((size_t)2 * NBLK * NE * 4);
  int*   blockbase = (int*)alloc((size_t)2 * NBLK * NE * 4);
  if (off > ws_size) return;   // ws too small -> will fail validation

  int* cntS = meta;           int* hbS = meta + NE;
  int* cntF = meta + 2 * NE;  int* hbF = meta + 3 * NE;

  transpose_cvt3_kernel<<<dim3(FFD / 32, DIMD / 32, 17), 256, 0, stream>>>(
      Ws1, W1s, W1f, ws1t, w1st, w1ft, DIMD, FFD);
  transpose_cvt3_kernel<<<dim3(DIMD / 32, FFD / 32, 17), 256, 0, stream>>>(
      Ws2, W2s, W2f, ws2t, w2st, w2ft, FFD, DIMD);
  router_kernel<<<N_TOK / 32, 256, 0, stream>>>(x, xb, WrS, brS, WrF, brF, expS, gS, expF, gF);
  scan_count_kernel<<<NBLK, 256, 0, stream>>>(expS, expF, blockcnt);
  scan_base_kernel<<<1, 64, 0, stream>>>(blockcnt, blockbase, meta);
  scan_write_kernel<<<NBLK, 256, 0, stream>>>(expS, expF, blockbase, idxS, idxF);

  // shared FFN (writes all of out)
  gemm_kernel<0, false, false><<<dim3(FFD / 256, N_TOK / 256), 1024, 0, stream>>>(
      xb, ws1t, bs1, nullptr, nullptr, nullptr, nullptr, hidden, nullptr);
  gemm_kernel<1, false, false><<<dim3(DIMD / 256, N_TOK / 256), 1024, 0, stream>>>(
      hidden, ws2t, bs2, nullptr, nullptr, nullptr, nullptr, nullptr, out);
  // spatial bank (adds into out)
  gemm_kernel<0, true, true><<<dim3(FFD / 256, NE * TPE2), 1024, 0, stream>>>(
      xb, w1st, b1s, idxS, cntS, hbS, nullptr, hidden, nullptr);
  gemm_kernel<2, false, true><<<dim3(DIMD / 256, NE * TPE2), 1024, 0, stream>>>(
      hidden, w2st, b2s, idxS, cntS, hbS, gS, nullptr, out);
  // spectral bank (adds into out)
  gemm_kernel<0, true, true><<<dim3(FFD / 256, NE * TPE2), 1024, 0, stream>>>(
      xb, w1ft, b1f, idxF, cntF, hbF, nullptr, hidden, nullptr);
  gemm_kernel<2, false, true><<<dim3(DIMD / 256, NE * TPE2), 1024, 0, stream>>>(
      hidden, w2ft, b2f, idxF, cntF, hbF, gF, nullptr, out);
}

// Round 13
// 700.416 us; speedup vs baseline: 1.3279x; 1.3279x over previous
//
#include <hip/hip_runtime.h>
#include <hip/hip_bf16.h>
#include <math.h>

// Problem constants
#define N_TOK 32768
#define DIMD  512
#define FFD   2048
#define NE    8
#define CAPQ  5120
#define TPE   40          // CAPQ / 128 row-tiles per expert
#define NBLK  128         // scan blocks (256 tokens each)

typedef __attribute__((ext_vector_type(8))) short          bf16x8;
typedef __attribute__((ext_vector_type(4))) float          f32x4;
typedef __attribute__((ext_vector_type(8))) unsigned short u16x8;

__device__ __forceinline__ unsigned short f2bf(float f) {
  union { float f; unsigned u; } v; v.f = f;
  unsigned r = v.u + 0x7fffu + ((v.u >> 16) & 1u);   // RNE (finite values only)
  return (unsigned short)(r >> 16);
}

// tanh-gelu in sigmoid form: 0.5v(1+tanh u) == v * sigma(2u), exact identity.
__device__ __forceinline__ float gelu_f(float v) {
  float t = v * v;
  float q = fmaf(-0.0713548162f, t, -1.5957691216f);   // -2*(a + b*t)
  float w = v * q;                                      // -2u
  float d = 1.0f + __expf(w);
  return v * __builtin_amdgcn_rcpf(d);
}

// async global->LDS, 16B/lane; LDS dest is wave-uniform base + lane*16
#define GLL16(gsrc, ldst)                                                      \
  __builtin_amdgcn_global_load_lds(                                            \
      (const __attribute__((address_space(1))) void*)(gsrc),                   \
      (__attribute__((address_space(3))) void*)(ldst), 16, 0, 0)

// ---- merged tiled transpose + f32->bf16: 17 slabs (1 shared + 8 + 8) -----
__global__ __launch_bounds__(256) void transpose_cvt3_kernel(
    const float* __restrict__ s0, const float* __restrict__ s1,
    const float* __restrict__ s2,
    unsigned short* __restrict__ d0, unsigned short* __restrict__ d1,
    unsigned short* __restrict__ d2, int R, int C) {
  __shared__ unsigned short tile[32][33];
  const int z = blockIdx.z;
  const float* in; unsigned short* out;
  if (z == 0)      { in = s0;                            out = d0; }
  else if (z <= 8) { in = s1 + (size_t)(z - 1) * R * C;  out = d1 + (size_t)(z - 1) * R * C; }
  else             { in = s2 + (size_t)(z - 9) * R * C;  out = d2 + (size_t)(z - 9) * R * C; }
  int c0 = blockIdx.x * 32, r0 = blockIdx.y * 32;
  int tx = threadIdx.x & 31, ty = threadIdx.x >> 5;   // 32x8
  #pragma unroll
  for (int i = 0; i < 4; i++) {
    int r = ty + i * 8;
    tile[r][tx] = f2bf(in[(size_t)(r0 + r) * C + c0 + tx]);
  }
  __syncthreads();
  #pragma unroll
  for (int i = 0; i < 4; i++) {
    int c = ty + i * 8;
    out[(size_t)(c0 + c) * R + r0 + tx] = tile[tx][c];
  }
}

// ---- router: logits, softmax, top-1, gate (both banks) + x->bf16 fused ---
__global__ __launch_bounds__(256) void router_kernel(
    const float* __restrict__ x, unsigned short* __restrict__ xb,
    const float* __restrict__ WrS, const float* __restrict__ brS,
    const float* __restrict__ WrF, const float* __restrict__ brF,
    int* __restrict__ expS, float* __restrict__ gateS,
    int* __restrict__ expF, float* __restrict__ gateF) {
  __shared__ float wS[DIMD * NE], wF[DIMD * NE];
  for (int i = threadIdx.x; i < DIMD * NE / 4; i += 256) {
    ((float4*)wS)[i] = ((const float4*)WrS)[i];
    ((float4*)wF)[i] = ((const float4*)WrF)[i];
  }
  __syncthreads();
  const int w = threadIdx.x >> 6, lane = threadIdx.x & 63;
  const int n0 = (blockIdx.x * 4 + w) * 8;       // 8 tokens per wave
  for (int t = 0; t < 8; t++) {
    const int n = n0 + t;
    const float* xr = x + (size_t)n * DIMD + lane * 8;
    float4 xa = *(const float4*)xr, xb4 = *(const float4*)(xr + 4);
    float xv[8] = {xa.x, xa.y, xa.z, xa.w, xb4.x, xb4.y, xb4.z, xb4.w};
    u16x8 xo;
    #pragma unroll
    for (int j = 0; j < 8; j++) xo[j] = f2bf(xv[j]);
    *(u16x8*)(xb + (size_t)n * DIMD + lane * 8) = xo;   // fused x->bf16
    float aS[NE], aF[NE];
    #pragma unroll
    for (int e = 0; e < NE; e++) { aS[e] = 0.f; aF[e] = 0.f; }
    #pragma unroll
    for (int j = 0; j < 8; j++) {
      const int k = lane * 8 + j;
      const float* ps = &wS[k * NE];
      const float* pf = &wF[k * NE];
      #pragma unroll
      for (int e = 0; e < NE; e++) { aS[e] += xv[j] * ps[e]; aF[e] += xv[j] * pf[e]; }
    }
    #pragma unroll
    for (int e = 0; e < NE; e++)
      for (int off = 32; off; off >>= 1) {
        aS[e] += __shfl_xor(aS[e], off);
        aF[e] += __shfl_xor(aF[e], off);
      }
    if (lane == 0) {
      float l[NE];
      #pragma unroll
      for (int e = 0; e < NE; e++) l[e] = aS[e] + brS[e];
      float m = l[0]; int am = 0;
      #pragma unroll
      for (int e = 1; e < NE; e++) if (l[e] > m) { m = l[e]; am = e; }  // first max
      float s = 0.f;
      #pragma unroll
      for (int e = 0; e < NE; e++) s += __expf(l[e] - m);
      expS[n] = am; gateS[n] = __builtin_amdgcn_rcpf(s);
      #pragma unroll
      for (int e = 0; e < NE; e++) l[e] = aF[e] + brF[e];
      m = l[0]; am = 0;
      #pragma unroll
      for (int e = 1; e < NE; e++) if (l[e] > m) { m = l[e]; am = e; }
      s = 0.f;
      #pragma unroll
      for (int e = 0; e < NE; e++) s += __expf(l[e] - m);
      expF[n] = am; gateF[n] = __builtin_amdgcn_rcpf(s);
    }
  }
}

// ------------- parallel stable capacity scan (3 kernels) ------------------
__global__ __launch_bounds__(256) void scan_count_kernel(
    const int* __restrict__ expS, const int* __restrict__ expF,
    int* __restrict__ blockcnt) {
  const int b = blockIdx.x, t = threadIdx.x;
  const int w = t >> 6, lane = t & 63;
  const int eS_ = expS[b * 256 + t], eF_ = expF[b * 256 + t];
  __shared__ int cnt[2][4][NE];
  #pragma unroll
  for (int q = 0; q < NE; q++) {
    unsigned long long mS = __ballot(eS_ == q);
    unsigned long long mF = __ballot(eF_ == q);
    if (lane == 0) { cnt[0][w][q] = __popcll(mS); cnt[1][w][q] = __popcll(mF); }
  }
  __syncthreads();
  if (t < 16) {
    const int bank = t >> 3, q = t & 7;
    blockcnt[bank * NBLK * NE + b * NE + q] =
        cnt[bank][0][q] + cnt[bank][1][q] + cnt[bank][2][q] + cnt[bank][3][q];
  }
}

// meta layout: [cntS 8][hbS 8][cntF 8][hbF 8]; hidden bases 128-aligned
__global__ __launch_bounds__(64) void scan_base_kernel(
    const int* __restrict__ blockcnt, int* __restrict__ blockbase,
    int* __restrict__ meta) {
  __shared__ int tot[2][NE];
  const int t = threadIdx.x;
  if (t < 16) {
    const int bank = t >> 3, q = t & 7;
    int run = 0;
    for (int i = 0; i < NBLK; i++) {
      int v = blockcnt[bank * NBLK * NE + i * NE + q];
      blockbase[bank * NBLK * NE + i * NE + q] = run;
      run += v;
    }
    tot[bank][q] = run;
  }
  __syncthreads();
  if (t == 0) {
    int hb_ = 0;
    for (int q = 0; q < NE; q++) {
      int cc = tot[0][q]; if (cc > CAPQ) cc = CAPQ;
      meta[q] = cc; meta[NE + q] = hb_;
      hb_ += ((cc + 127) >> 7) << 7;          // 128-aligned hidden base
    }
    hb_ = 0;
    for (int q = 0; q < NE; q++) {
      int cc = tot[1][q]; if (cc > CAPQ) cc = CAPQ;
      meta[2 * NE + q] = cc; meta[3 * NE + q] = hb_;
      hb_ += ((cc + 127) >> 7) << 7;
    }
  }
}

__global__ __launch_bounds__(256) void scan_write_kernel(
    const int* __restrict__ expS, const int* __restrict__ expF,
    const int* __restrict__ blockbase,
    int* __restrict__ idxS, int* __restrict__ idxF) {
  const int b = blockIdx.x, t = threadIdx.x;
  const int w = t >> 6, lane = t & 63;
  const int n = b * 256 + t;
  const int eS_ = expS[n], eF_ = expF[n];
  __shared__ int wcnt[2][4][NE];
  const unsigned long long ltmask = ((unsigned long long)1 << lane) - 1;
  int rS = 0, rF = 0;
  #pragma unroll
  for (int q = 0; q < NE; q++) {
    unsigned long long mS = __ballot(eS_ == q);
    unsigned long long mF = __ballot(eF_ == q);
    if (eS_ == q) rS = __popcll(mS & ltmask);
    if (eF_ == q) rF = __popcll(mF & ltmask);
    if (lane == 0) { wcnt[0][w][q] = __popcll(mS); wcnt[1][w][q] = __popcll(mF); }
  }
  __syncthreads();
  int pS = blockbase[0 * NBLK * NE + b * NE + eS_] + rS;
  int pF = blockbase[1 * NBLK * NE + b * NE + eF_] + rF;
  #pragma unroll
  for (int wv = 0; wv < 4; wv++) {
    if (wv < w) { pS += wcnt[0][wv][eS_]; pF += wcnt[1][wv][eF_]; }
  }
  if (pS < CAPQ) idxS[eS_ * CAPQ + pS] = n;
  if (pF < CAPQ) idxF[eF_ * CAPQ + pF] = n;
}

// --- MFMA GEMM, 128x128 tile, BK=64, 8 waves (4x2), SINGLE 32 KB buffer --
// m97 occupancy mechanism: 32 KB LDS + ~52 regs -> 4 blocks x 8 waves =
// 32 waves/CU; cross-block TLP hides the serialized stage->compute tile.
// Sync: stage (4 GLL16/thread) -> __syncthreads (drains vmcnt) -> ds_read +
// MFMA -> __syncthreads (protects buffer overwrite). Proven chunk-XOR
// swizzle both sides (0 conflicts across 11 rounds).
// EPI 0: C = gelu(A@Bt^T + bias) -> hidden bf16     (K=DIMD, NC=FFD)
// EPI 1: out = A@Bt^T + bias (f32 write)            (K=FFD,  NC=DIMD)
// EPI 2: out[tok] += (A@Bt^T + bias) * gate[tok]    (K=FFD,  NC=DIMD)
template <int EPI, bool GATHER, bool BANKED>
__global__ __launch_bounds__(512, 6) void gemm_kernel(
    const unsigned short* __restrict__ A,
    const unsigned short* __restrict__ Bt,   // [(e)][NC][K] bf16 (pre-transposed)
    const float* __restrict__ bias,          // [(e)][NC]
    const int* __restrict__ idx, const int* __restrict__ cnt,
    const int* __restrict__ hb, const float* __restrict__ gate,
    unsigned short* __restrict__ hidOut, float* __restrict__ fOut) {
  constexpr int K  = (EPI == 0) ? DIMD : FFD;
  constexpr int NC = (EPI == 0) ? FFD : DIMD;
  constexpr int NT = K / 64;

  __shared__ __align__(16) unsigned short lA[128 * 64];  // 16 KiB
  __shared__ __align__(16) unsigned short lB[128 * 64];  // 16 KiB

  const int tid = threadIdx.x;
  const int w = tid >> 6, lane = tid & 63;

  // bijective XCD-chunked block swizzle (m204)
  const int gx = gridDim.x;
  const int nwg = gx * gridDim.y;
  int flat = blockIdx.y * gx + blockIdx.x;
  {
    const int q8 = nwg >> 3, r8 = nwg & 7;
    const int xcd = flat & 7, loc = flat >> 3;
    flat = (xcd < r8 ? xcd * (q8 + 1) : r8 * (q8 + 1) + (xcd - r8) * q8) + loc;
  }
  const int bx = flat % gx, by = flat / gx;

  int e = 0, r0, cnte = 0;
  if (BANKED) {
    e = by / TPE;
    r0 = (by - e * TPE) * 128;
    cnte = cnt[e];
    if (r0 >= cnte) return;
  } else {
    r0 = by * 128;
  }

  // --- staging: chunk ci = i*8+w covers rows [ci*8, ci*8+8); 2 chunks/wave
  const int srow = lane >> 3;            // row within 8-row chunk
  const int sch  = (lane & 7) ^ srow;    // pre-swizzled global chunk (rule #21)
  const unsigned short* aP[2];
  const unsigned short* bP[2];
  const size_t bcol0 = (size_t)(BANKED ? e * NC : 0) + (size_t)bx * 128;
  #pragma unroll
  for (int i = 0; i < 2; i++) {
    const int ri = (i * 8 + w) * 8 + srow;   // row within tile
    size_t arow;
    if (GATHER) {
      int s = r0 + ri;
      int tok = (s < cnte) ? idx[e * CAPQ + s] : 0;
      arow = (size_t)tok;
    } else if (BANKED) {
      arow = (size_t)(hb[e] + r0 + ri);
    } else {
      arow = (size_t)(r0 + ri);
    }
    aP[i] = A + arow * K + sch * 8;
    bP[i] = Bt + (bcol0 + ri) * K + sch * 8;
  }

  f32x4 acc[2][4];
  #pragma unroll
  for (int m = 0; m < 2; m++)
    #pragma unroll
    for (int n = 0; n < 4; n++) acc[m][n] = (f32x4){0.f, 0.f, 0.f, 0.f};

  const int wr = w >> 1, wc = w & 1;       // wave: rows wr*32.., cols wc*64..
  const int grp = lane >> 4, l15 = lane & 15;
  const int swz = l15 & 7;
  int aoff[2], boff[4], kche[2];
  #pragma unroll
  for (int m = 0; m < 2; m++) aoff[m] = (wr * 32 + m * 16 + l15) * 64;
  #pragma unroll
  for (int n = 0; n < 4; n++) boff[n] = (wc * 64 + n * 16 + l15) * 64;
  #pragma unroll
  for (int kk = 0; kk < 2; kk++) kche[kk] = ((kk * 4 + grp) ^ swz) * 8;

  char* const la = (char*)&lA[0] + (unsigned)w * 1024;
  char* const lb = (char*)&lB[0] + (unsigned)w * 1024;

  #pragma unroll 1
  for (int t = 0; t < NT; t++) {
    const int k0 = t * 64;
    #pragma unroll
    for (int i = 0; i < 2; i++) {
      GLL16(aP[i] + k0, la + i * 8192);
      GLL16(bP[i] + k0, lb + i * 8192);
    }
    __syncthreads();                       // drains vmcnt; tile t visible
    #pragma unroll
    for (int kk = 0; kk < 2; kk++) {
      const int co = kche[kk];
      bf16x8 af[2], bfv[4];
      #pragma unroll
      for (int m = 0; m < 2; m++) af[m] = *(const bf16x8*)&lA[aoff[m] + co];
      #pragma unroll
      for (int n = 0; n < 4; n++) bfv[n] = *(const bf16x8*)&lB[boff[n] + co];
      __builtin_amdgcn_s_setprio(1);
      #pragma unroll
      for (int m = 0; m < 2; m++)
        #pragma unroll
        for (int n = 0; n < 4; n++)
          acc[m][n] = __builtin_amdgcn_mfma_f32_16x16x32_bf16(af[m], bfv[n], acc[m][n], 0, 0, 0);
      __builtin_amdgcn_s_setprio(0);
    }
    __syncthreads();                       // all waves done reading buffer
  }

  // --- epilogue: C/D layout col=lane&15, row=(lane>>4)*4+j (m89-verified)
  const int grp4 = grp * 4;
  if constexpr (EPI == 0) {
    const size_t hrow0 = (size_t)((BANKED ? hb[e] : 0) + r0);
    const float* bP2 = bias + (BANKED ? e * NC : 0) + bx * 128;
    #pragma unroll
    for (int m = 0; m < 2; m++)
      #pragma unroll
      for (int j = 0; j < 4; j++) {
        const int rloc = wr * 32 + m * 16 + grp4 + j;
        unsigned short* hrow = hidOut + (hrow0 + rloc) * FFD + bx * 128;
        #pragma unroll
        for (int n = 0; n < 4; n++) {
          const int cloc = wc * 64 + n * 16 + l15;
          float v = acc[m][n][j] + bP2[cloc];
          hrow[cloc] = f2bf(gelu_f(v));
        }
      }
  } else if constexpr (EPI == 1) {
    const float* bP2 = bias + bx * 128;
    #pragma unroll
    for (int m = 0; m < 2; m++)
      #pragma unroll
      for (int j = 0; j < 4; j++) {
        const int rloc = wr * 32 + m * 16 + grp4 + j;
        float* orow = fOut + (size_t)(r0 + rloc) * DIMD + bx * 128;
        #pragma unroll
        for (int n = 0; n < 4; n++) {
          const int cloc = wc * 64 + n * 16 + l15;
          orow[cloc] = acc[m][n][j] + bP2[cloc];
        }
      }
  } else {
    const float* bP2 = bias + e * NC + bx * 128;
    const int* idxe = idx + e * CAPQ + r0;
    #pragma unroll
    for (int m = 0; m < 2; m++)
      #pragma unroll
      for (int j = 0; j < 4; j++) {
        const int rloc = wr * 32 + m * 16 + grp4 + j;
        if (r0 + rloc < cnte) {
          const int tok = idxe[rloc];
          const float gv = gate[tok];
          float* orow = fOut + (size_t)tok * DIMD + bx * 128;
          #pragma unroll
          for (int n = 0; n < 4; n++) {
            const int cloc = wc * 64 + n * 16 + l15;
            orow[cloc] += (acc[m][n][j] + bP2[cloc]) * gv;  // unique (tok,col)
          }
        }
      }
  }
}

extern "C" void kernel_launch(void* const* d_in, const int* in_sizes, int n_in,
                              void* d_out, int out_size, void* d_ws, size_t ws_size,
                              hipStream_t stream) {
  const float* x   = (const float*)d_in[0];
  const float* WrS = (const float*)d_in[1];
  const float* brS = (const float*)d_in[2];
  const float* WrF = (const float*)d_in[3];
  const float* brF = (const float*)d_in[4];
  const float* Ws1 = (const float*)d_in[5];
  const float* bs1 = (const float*)d_in[6];
  const float* Ws2 = (const float*)d_in[7];
  const float* bs2 = (const float*)d_in[8];
  const float* W1s = (const float*)d_in[9];
  const float* b1s = (const float*)d_in[10];
  const float* W2s = (const float*)d_in[11];
  const float* b2s = (const float*)d_in[12];
  const float* W1f = (const float*)d_in[13];
  const float* b1f = (const float*)d_in[14];
  const float* W2f = (const float*)d_in[15];
  const float* b2f = (const float*)d_in[16];
  float* out = (float*)d_out;

  char* ws = (char*)d_ws;
  size_t off = 0;
  auto alloc = [&](size_t b) { char* p = ws + off; off += (b + 255) & ~(size_t)255; return p; };
  unsigned short* xb     = (unsigned short*)alloc((size_t)N_TOK * DIMD * 2);
  unsigned short* ws1t   = (unsigned short*)alloc((size_t)FFD * DIMD * 2);
  unsigned short* ws2t   = (unsigned short*)alloc((size_t)DIMD * FFD * 2);
  unsigned short* w1st   = (unsigned short*)alloc((size_t)NE * FFD * DIMD * 2);
  unsigned short* w2st   = (unsigned short*)alloc((size_t)NE * DIMD * FFD * 2);
  unsigned short* w1ft   = (unsigned short*)alloc((size_t)NE * FFD * DIMD * 2);
  unsigned short* w2ft   = (unsigned short*)alloc((size_t)NE * DIMD * FFD * 2);
  unsigned short* hidden = (unsigned short*)alloc((size_t)(N_TOK + NE * 128) * FFD * 2);
  int*   expS = (int*)alloc((size_t)N_TOK * 4);
  int*   expF = (int*)alloc((size_t)N_TOK * 4);
  float* gS   = (float*)alloc((size_t)N_TOK * 4);
  float* gF   = (float*)alloc((size_t)N_TOK * 4);
  int*   idxS = (int*)alloc((size_t)NE * CAPQ * 4);
  int*   idxF = (int*)alloc((size_t)NE * CAPQ * 4);
  int*   meta = (int*)alloc(4 * NE * 4);
  int*   blockcnt  = (int*)alloc((size_t)2 * NBLK * NE * 4);
  int*   blockbase = (int*)alloc((size_t)2 * NBLK * NE * 4);
  if (off > ws_size) return;   // ws too small -> will fail validation

  int* cntS = meta;           int* hbS = meta + NE;
  int* cntF = meta + 2 * NE;  int* hbF = meta + 3 * NE;

  transpose_cvt3_kernel<<<dim3(FFD / 32, DIMD / 32, 17), 256, 0, stream>>>(
      Ws1, W1s, W1f, ws1t, w1st, w1ft, DIMD, FFD);
  transpose_cvt3_kernel<<<dim3(DIMD / 32, FFD / 32, 17), 256, 0, stream>>>(
      Ws2, W2s, W2f, ws2t, w2st, w2ft, FFD, DIMD);
  router_kernel<<<N_TOK / 32, 256, 0, stream>>>(x, xb, WrS, brS, WrF, brF, expS, gS, expF, gF);
  scan_count_kernel<<<NBLK, 256, 0, stream>>>(expS, expF, blockcnt);
  scan_base_kernel<<<1, 64, 0, stream>>>(blockcnt, blockbase, meta);
  scan_write_kernel<<<NBLK, 256, 0, stream>>>(expS, expF, blockbase, idxS, idxF);

  // shared FFN (writes all of out)
  gemm_kernel<0, false, false><<<dim3(FFD / 128, N_TOK / 128), 512, 0, stream>>>(
      xb, ws1t, bs1, nullptr, nullptr, nullptr, nullptr, hidden, nullptr);
  gemm_kernel<1, false, false><<<dim3(DIMD / 128, N_TOK / 128), 512, 0, stream>>>(
      hidden, ws2t, bs2, nullptr, nullptr, nullptr, nullptr, nullptr, out);
  // spatial bank (adds into out)
  gemm_kernel<0, true, true><<<dim3(FFD / 128, NE * TPE), 512, 0, stream>>>(
      xb, w1st, b1s, idxS, cntS, hbS, nullptr, hidden, nullptr);
  gemm_kernel<2, false, true><<<dim3(DIMD / 128, NE * TPE), 512, 0, stream>>>(
      hidden, w2st, b2s, idxS, cntS, hbS, gS, nullptr, out);
  // spectral bank (adds into out)
  gemm_kernel<0, true, true><<<dim3(FFD / 128, NE * TPE), 512, 0, stream>>>(
      xb, w1ft, b1f, idxF, cntF, hbF, nullptr, hidden, nullptr);
  gemm_kernel<2, false, true><<<dim3(DIMD / 128, NE * TPE), 512, 0, stream>>>(
      hidden, w2ft, b2f, idxF, cntF, hbF, gF, nullptr, out);
}